// Round 1
// baseline (824.091 us; speedup 1.0000x reference)
//
#include <hip/hip_runtime.h>
#include <hip/hip_bf16.h>

#define B_   8
#define H_   128
#define W_   128
#define C_   64
#define F_   128
#define KK_  9
#define CS_  576      // KK_*C_
#define KDIM 5184     // 9*CS_
#define HP   130
#define WP   130

typedef __bf16 bf16x8 __attribute__((ext_vector_type(8)));
typedef float  f32x4  __attribute__((ext_vector_type(4)));

__device__ __forceinline__ unsigned short f2bf(float f) {
  unsigned int u = __float_as_uint(f);
  unsigned int r = (u + 0x7fffu + ((u >> 16) & 1u)) >> 16;
  return (unsigned short)r;
}

// ---------------- offset conv: offs[b,h,w,18] = SAME conv3x3(x, W_off) + b_off
__global__ __launch_bounds__(128) void offs_conv_kernel(
    const float* __restrict__ x, const float* __restrict__ Woff,
    const float* __restrict__ boff, float* __restrict__ offs) {
  __shared__ float Wl[9 * 18 * 64];   // [tap][o][c]
  const int w = threadIdx.x;
  const int h = blockIdx.x;
  const int b = blockIdx.y;
  for (int i = threadIdx.x; i < 9 * 64 * 18; i += 128) {
    int tap = i / 1152;
    int r   = i % 1152;
    int c   = r / 18;
    int o   = r % 18;
    Wl[(tap * 18 + o) * 64 + c] = Woff[i];
  }
  __syncthreads();
  float acc[18];
#pragma unroll
  for (int o = 0; o < 18; ++o) acc[o] = boff[o];
  for (int ky = 0; ky < 3; ++ky) {
    int hy = h + ky - 1;
    if (hy < 0 || hy >= H_) continue;
    for (int kx = 0; kx < 3; ++kx) {
      int wx = w + kx - 1;
      if (wx < 0 || wx >= W_) continue;
      const float* xp = x + (((size_t)(b * H_ + hy) * W_ + wx) * C_);
      const float* wl = &Wl[(ky * 3 + kx) * 18 * 64];
      for (int c = 0; c < 64; c += 4) {
        float4 xv = *(const float4*)(xp + c);
#pragma unroll
        for (int o = 0; o < 18; ++o) {
          const float4 wv = *(const float4*)(wl + o * 64 + c);
          acc[o] += xv.x * wv.x + xv.y * wv.y + xv.z * wv.z + xv.w * wv.w;
        }
      }
    }
  }
  float* op = offs + (((size_t)(b * H_ + h) * W_ + w) * 18);
#pragma unroll
  for (int o = 0; o < 18; ++o) op[o] = acc[o];
}

// ---------------- W (5184,128) fp32 -> Wt (128,5184) bf16
__global__ __launch_bounds__(256) void wt_prep_kernel(
    const float* __restrict__ Wf, unsigned short* __restrict__ Wt) {
  int tid = blockIdx.x * 256 + threadIdx.x;
  if (tid >= KDIM * F_) return;
  int f  = tid % F_;
  int kk = tid / F_;
  Wt[(size_t)f * KDIM + kk] = f2bf(Wf[tid]);
}

// ---------------- zero the 1-pixel border of padded sampled
__global__ __launch_bounds__(256) void border_zero_kernel(
    unsigned short* __restrict__ sp, int nb) {
  int tid = blockIdx.x * 256 + threadIdx.x;
  int total = nb * 516 * 9;
  if (tid >= total) return;
  int cc  = (tid % 9) * 64;
  int pix = tid / 9;
  int bl  = pix / 516;
  int p   = pix % 516;
  int hp, wp;
  if (p < 130)      { hp = 0;   wp = p; }
  else if (p < 260) { hp = 129; wp = p - 130; }
  else { int q = p - 260; hp = 1 + (q >> 1); wp = (q & 1) ? 129 : 0; }
  unsigned short* dst = sp + ((size_t)(bl * HP + hp) * WP + wp) * CS_ + cc;
  uint4 z = {0u, 0u, 0u, 0u};
#pragma unroll
  for (int i = 0; i < 8; ++i) ((uint4*)dst)[i] = z;
}

// ---------------- bilinear sampling -> padded bf16 sampled (nb,130,130,576)
__global__ __launch_bounds__(256) void sample_kernel(
    const float* __restrict__ x, const float* __restrict__ offs,
    unsigned short* __restrict__ sp, int b0, int nb) {
  int tid = blockIdx.x * 256 + threadIdx.x;
  int total = nb * H_ * W_ * KK_;
  if (tid >= total) return;
  int t  = tid % 9;
  int w  = (tid / 9) % W_;
  int h  = (tid / (9 * W_)) % H_;
  int bl = tid / (9 * W_ * H_);
  int b  = b0 + bl;
  const float* op = offs + (((size_t)(b * H_ + h) * W_ + w) * 18 + 2 * t);
  float offx = op[0], offy = op[1];
  float lx = (float)w + (float)(t % 3 - 1) + offx;
  float ly = (float)h + (float)(t / 3 - 1) + offy;
  lx = fminf(fmaxf(lx, 0.f), 127.f);
  ly = fminf(fmaxf(ly, 0.f), 127.f);
  float fx = floorf(lx), fy = floorf(ly);
  float x0 = fminf(fmaxf(fx, 0.f), 127.f);
  float x1 = fminf(fmaxf(fx + 1.f, 0.f), 127.f);
  float y0 = fminf(fmaxf(fy, 0.f), 127.f);
  float y1 = fminf(fmaxf(fy + 1.f, 0.f), 127.f);
  float wa = (x1 - lx) * (y1 - ly);
  float wb = (x1 - lx) * (ly - y0);
  float wc = (lx - x0) * (y1 - ly);
  float wd = (lx - x0) * (ly - y0);
  int ix0 = (int)x0, ix1 = (int)x1, iy0 = (int)y0, iy1 = (int)y1;
  const float* xb = x + (size_t)b * (H_ * W_ * C_);
  const float* pa = xb + ((size_t)iy0 * W_ + ix0) * C_;
  const float* pb = xb + ((size_t)iy1 * W_ + ix0) * C_;
  const float* pc = xb + ((size_t)iy0 * W_ + ix1) * C_;
  const float* pd = xb + ((size_t)iy1 * W_ + ix1) * C_;
  unsigned short* out = sp + ((size_t)(bl * HP + h + 1) * WP + (w + 1)) * CS_ + t * 64;
  for (int c = 0; c < 64; c += 4) {
    float4 A  = *(const float4*)(pa + c);
    float4 Bv = *(const float4*)(pb + c);
    float4 Cv = *(const float4*)(pc + c);
    float4 D  = *(const float4*)(pd + c);
    ushort4 u;
    u.x = f2bf(wa * A.x + wb * Bv.x + wc * Cv.x + wd * D.x);
    u.y = f2bf(wa * A.y + wb * Bv.y + wc * Cv.y + wd * D.y);
    u.z = f2bf(wa * A.z + wb * Bv.z + wc * Cv.z + wd * D.z);
    u.w = f2bf(wa * A.w + wb * Bv.w + wc * Cv.w + wd * D.w);
    *(ushort4*)(out + c) = u;
  }
}

// ---------------- implicit-im2col MFMA GEMM: out[p,f] = sum_k A[p,k]*W[k,f] + b[f]
// M-tile = 128 px (one image row), N = 128 (all F), BK = 64.
__global__ __launch_bounds__(256, 2) void gemm_kernel(
    const unsigned short* __restrict__ sp,   // (nb,130,130,576) bf16
    const unsigned short* __restrict__ Wt,   // (128,5184) bf16
    const float* __restrict__ bias,
    float* __restrict__ out, int b0) {
  __shared__ __align__(16) short lds[16384]; // A:[0,8192) B:[8192,16384) shorts
  const int tid  = threadIdx.x;
  const int lane = tid & 63;
  const int wv   = tid >> 6;
  const int bl   = blockIdx.x / H_;
  const int h    = blockIdx.x % H_;
  const int wm   = (wv >> 1) * 64;
  const int wn   = (wv & 1) * 64;
  const int l15  = lane & 15;
  const int quad = lane >> 4;
  const int sub  = lane & 7;
  const int rig  = lane >> 3;   // row-in-group for staging

  f32x4 acc[4][4] = {};

  // LDS fragment read offsets (in shorts), XOR-swizzled
  int a_addr[2][4], b_addr[2][4];
#pragma unroll
  for (int ks = 0; ks < 2; ++ks) {
#pragma unroll
    for (int i = 0; i < 4; ++i) {
      int m = wm + 16 * i + l15;
      int q = ks * 4 + quad;
      a_addr[ks][i] = m * 64 + (q ^ (m & 7)) * 8;
      int n = wn + 16 * i + l15;
      b_addr[ks][i] = 8192 + n * 64 + (q ^ (n & 7)) * 8;
    }
  }

  // staging row/swizzle per instruction (4 A + 4 B per wave)
  int am[4], asg[4];
  const short* gB[4];
#pragma unroll
  for (int i = 0; i < 4; ++i) {
    int m  = wv * 32 + i * 8 + rig;
    am[i]  = m;
    asg[i] = (sub ^ (m & 7)) * 8;
    gB[i]  = (const short*)Wt + (size_t)m * KDIM + (sub ^ (m & 7)) * 8;
  }

  for (int tap = 0; tap < 9; ++tap) {
    const int ky = tap / 3, kx = tap % 3;
    const short* gA[4];
#pragma unroll
    for (int i = 0; i < 4; ++i)
      gA[i] = (const short*)sp +
              ((size_t)((bl * HP + h + ky) * WP) + (am[i] + kx)) * CS_ + asg[i];
    for (int tcs = 0; tcs < 9; ++tcs) {
      __syncthreads();   // all waves done reading previous tile
#pragma unroll
      for (int i = 0; i < 4; ++i) {
        __builtin_amdgcn_global_load_lds(
            (const __attribute__((address_space(1))) void*)(gA[i]),
            (__attribute__((address_space(3))) void*)&lds[(wv * 32 + i * 8) * 64],
            16, 0, 0);
        gA[i] += 64;
      }
#pragma unroll
      for (int i = 0; i < 4; ++i) {
        __builtin_amdgcn_global_load_lds(
            (const __attribute__((address_space(1))) void*)(gB[i]),
            (__attribute__((address_space(3))) void*)&lds[8192 + (wv * 32 + i * 8) * 64],
            16, 0, 0);
        gB[i] += 64;
      }
      __syncthreads();   // staged data visible
#pragma unroll
      for (int ks = 0; ks < 2; ++ks) {
        bf16x8 af[4], bf[4];
#pragma unroll
        for (int i = 0; i < 4; ++i) af[i] = *(const bf16x8*)&lds[a_addr[ks][i]];
#pragma unroll
        for (int j = 0; j < 4; ++j) bf[j] = *(const bf16x8*)&lds[b_addr[ks][j]];
#pragma unroll
        for (int i = 0; i < 4; ++i)
#pragma unroll
          for (int j = 0; j < 4; ++j)
            acc[i][j] = __builtin_amdgcn_mfma_f32_16x16x32_bf16(
                af[i], bf[j], acc[i][j], 0, 0, 0);
      }
    }
  }

  // epilogue: C row = quad*4+r, col = lane&15 (within each 16x16 frag)
  const int b = b0 + bl;
  float bj[4];
#pragma unroll
  for (int j = 0; j < 4; ++j) bj[j] = bias[wn + 16 * j + l15];
  float* op = out + (size_t)(b * H_ + h) * W_ * F_;
#pragma unroll
  for (int i = 0; i < 4; ++i) {
#pragma unroll
    for (int r = 0; r < 4; ++r) {
      int m = wm + 16 * i + quad * 4 + r;
      float* rp = op + (size_t)m * F_;
#pragma unroll
      for (int j = 0; j < 4; ++j)
        rp[wn + 16 * j + l15] = acc[i][j][r] + bj[j];
    }
  }
}

extern "C" void kernel_launch(void* const* d_in, const int* in_sizes, int n_in,
                              void* d_out, int out_size, void* d_ws, size_t ws_size,
                              hipStream_t stream) {
  (void)in_sizes; (void)n_in; (void)out_size;
  const float* x    = (const float*)d_in[0];
  const float* Woff = (const float*)d_in[1];
  const float* boff = (const float*)d_in[2];
  const float* Wf   = (const float*)d_in[3];
  const float* bias = (const float*)d_in[4];
  float* out = (float*)d_out;

  char* ws = (char*)d_ws;
  size_t off_bytes = (size_t)B_ * H_ * W_ * 18 * 4;  // 9.44 MB
  size_t wt_bytes  = (size_t)F_ * KDIM * 2;          // 1.33 MB
  size_t p1 = (off_bytes + 255) & ~(size_t)255;
  size_t p2 = (p1 + wt_bytes + 255) & ~(size_t)255;
  float*          offs = (float*)ws;
  unsigned short* Wt   = (unsigned short*)(ws + p1);
  unsigned short* sp   = (unsigned short*)(ws + p2);

  size_t per_batch = (size_t)HP * WP * CS_ * 2;      // 19.47 MB
  size_t avail = (ws_size > p2) ? (ws_size - p2) : 0;
  int nb = (int)(avail / per_batch);
  if (nb < 1) nb = 1;
  if (nb > B_) nb = B_;

  offs_conv_kernel<<<dim3(H_, B_), 128, 0, stream>>>(x, Woff, boff, offs);
  wt_prep_kernel<<<(KDIM * F_ + 255) / 256, 256, 0, stream>>>(Wf, Wt);

  for (int b0 = 0; b0 < B_; b0 += nb) {
    int cur = (B_ - b0 < nb) ? (B_ - b0) : nb;
    int bzN = cur * 516 * 9;
    border_zero_kernel<<<(bzN + 255) / 256, 256, 0, stream>>>(sp, cur);
    int smN = cur * H_ * W_ * KK_;
    sample_kernel<<<(smN + 255) / 256, 256, 0, stream>>>(x, offs, sp, b0, cur);
    gemm_kernel<<<cur * H_, 256, 0, stream>>>(sp, Wt, bias, out, b0);
  }
}

// Round 2
// 509.898 us; speedup vs baseline: 1.6162x; 1.6162x over previous
//
#include <hip/hip_runtime.h>
#include <hip/hip_bf16.h>

#define B_   8
#define H_   128
#define W_   128
#define C_   64
#define F_   128
#define KK_  9
#define CS_  576      // KK_*C_
#define KDIM 5184     // 9*CS_
#define HP   130
#define WP   130

typedef __bf16 bf16x8 __attribute__((ext_vector_type(8)));
typedef float  f32x4  __attribute__((ext_vector_type(4)));

__device__ __forceinline__ unsigned short f2bf(float f) {
  unsigned int u = __float_as_uint(f);
  unsigned int r = (u + 0x7fffu + ((u >> 16) & 1u)) >> 16;
  return (unsigned short)r;
}

// ---------------- offset conv: offs[b,h,w,18] = SAME conv3x3(x, W_off) + b_off
// 4 lanes per pixel (16 ch each): coalesced x reads, shuffle-reduce the 18 sums.
__global__ __launch_bounds__(256) void offs_conv_kernel(
    const float* __restrict__ x, const float* __restrict__ Woff,
    const float* __restrict__ boff, float* __restrict__ offs) {
  __shared__ float Wl[9 * 18 * 64];   // [tap][o][c]
  const int tid = threadIdx.x;
  for (int i = tid; i < 9 * 64 * 18; i += 256) {
    int tap = i / 1152;
    int r   = i % 1152;
    int c   = r / 18;
    int o   = r % 18;
    Wl[(tap * 18 + o) * 64 + c] = Woff[i];
  }
  __syncthreads();
  const int gpix = blockIdx.x * 64 + (tid >> 2);
  const int q    = tid & 3;
  const int c0   = q * 16;
  const int w = gpix % W_;
  const int h = (gpix / W_) % H_;
  const int b = gpix / (W_ * H_);
  float acc[18] = {};
  for (int ky = 0; ky < 3; ++ky) {
    int hy = h + ky - 1;
    if (hy < 0 || hy >= H_) continue;
    for (int kx = 0; kx < 3; ++kx) {
      int wx = w + kx - 1;
      if (wx < 0 || wx >= W_) continue;
      const float* xp = x + ((size_t)(b * H_ + hy) * W_ + wx) * C_ + c0;
      const float* wl = &Wl[(ky * 3 + kx) * 18 * 64 + c0];
      float4 xv0 = *(const float4*)(xp + 0);
      float4 xv1 = *(const float4*)(xp + 4);
      float4 xv2 = *(const float4*)(xp + 8);
      float4 xv3 = *(const float4*)(xp + 12);
#pragma unroll
      for (int o = 0; o < 18; ++o) {
        const float4* wv = (const float4*)(wl + o * 64);
        float4 w0 = wv[0], w1 = wv[1], w2 = wv[2], w3 = wv[3];
        acc[o] += xv0.x * w0.x + xv0.y * w0.y + xv0.z * w0.z + xv0.w * w0.w
                + xv1.x * w1.x + xv1.y * w1.y + xv1.z * w1.z + xv1.w * w1.w
                + xv2.x * w2.x + xv2.y * w2.y + xv2.z * w2.z + xv2.w * w2.w
                + xv3.x * w3.x + xv3.y * w3.y + xv3.z * w3.z + xv3.w * w3.w;
      }
    }
  }
#pragma unroll
  for (int o = 0; o < 18; ++o) {
    acc[o] += __shfl_xor(acc[o], 1);
    acc[o] += __shfl_xor(acc[o], 2);
  }
  float* op = offs + (size_t)gpix * 18;
  for (int o = q; o < 18; o += 4) op[o] = acc[o] + boff[o];
}

// ---------------- W (5184,128) fp32 -> Wt (128,5184) bf16
__global__ __launch_bounds__(256) void wt_prep_kernel(
    const float* __restrict__ Wf, unsigned short* __restrict__ Wt) {
  int tid = blockIdx.x * 256 + threadIdx.x;
  if (tid >= KDIM * F_) return;
  int f  = tid % F_;
  int kk = tid / F_;
  Wt[(size_t)f * KDIM + kk] = f2bf(Wf[tid]);
}

// ---------------- zero the 1-pixel border of padded sampled
__global__ __launch_bounds__(256) void border_zero_kernel(
    unsigned short* __restrict__ sp, int nb) {
  int tid = blockIdx.x * 256 + threadIdx.x;
  int total = nb * 516 * 9;
  if (tid >= total) return;
  int cc  = (tid % 9) * 64;
  int pix = tid / 9;
  int bl  = pix / 516;
  int p   = pix % 516;
  int hp, wp;
  if (p < 130)      { hp = 0;   wp = p; }
  else if (p < 260) { hp = 129; wp = p - 130; }
  else { int q = p - 260; hp = 1 + (q >> 1); wp = (q & 1) ? 129 : 0; }
  unsigned short* dst = sp + ((size_t)(bl * HP + hp) * WP + wp) * CS_ + cc;
  uint4 z = {0u, 0u, 0u, 0u};
#pragma unroll
  for (int i = 0; i < 8; ++i) ((uint4*)dst)[i] = z;
}

// ---------------- bilinear sampling -> padded bf16 sampled (nb,130,130,576)
// 16 lanes per (pixel,tap), 4 channels/lane: coalesced gathers and stores.
__global__ __launch_bounds__(256) void sample_kernel(
    const float* __restrict__ x, const float* __restrict__ offs,
    unsigned short* __restrict__ sp, int b0, int nb) {
  int gid = blockIdx.x * 16 + (threadIdx.x >> 4);
  int l   = threadIdx.x & 15;
  int total = nb * H_ * W_ * KK_;
  if (gid >= total) return;
  int t  = gid % 9;
  int w  = (gid / 9) % W_;
  int h  = (gid / (9 * W_)) % H_;
  int bl = gid / (9 * W_ * H_);
  int b  = b0 + bl;
  const float* op = offs + (((size_t)(b * H_ + h) * W_ + w) * 18 + 2 * t);
  float offx = op[0], offy = op[1];
  float lx = (float)w + (float)(t % 3 - 1) + offx;
  float ly = (float)h + (float)(t / 3 - 1) + offy;
  lx = fminf(fmaxf(lx, 0.f), 127.f);
  ly = fminf(fmaxf(ly, 0.f), 127.f);
  float fx = floorf(lx), fy = floorf(ly);
  float x0 = fminf(fmaxf(fx, 0.f), 127.f);
  float x1 = fminf(fmaxf(fx + 1.f, 0.f), 127.f);
  float y0 = fminf(fmaxf(fy, 0.f), 127.f);
  float y1 = fminf(fmaxf(fy + 1.f, 0.f), 127.f);
  float wa = (x1 - lx) * (y1 - ly);
  float wb = (x1 - lx) * (ly - y0);
  float wc = (lx - x0) * (y1 - ly);
  float wd = (lx - x0) * (ly - y0);
  int ix0 = (int)x0, ix1 = (int)x1, iy0 = (int)y0, iy1 = (int)y1;
  const float* xb = x + (size_t)b * (H_ * W_ * C_);
  const int c = l * 4;
  const float* pa = xb + ((size_t)iy0 * W_ + ix0) * C_ + c;
  const float* pb = xb + ((size_t)iy1 * W_ + ix0) * C_ + c;
  const float* pc = xb + ((size_t)iy0 * W_ + ix1) * C_ + c;
  const float* pd = xb + ((size_t)iy1 * W_ + ix1) * C_ + c;
  float4 A  = *(const float4*)pa;
  float4 Bv = *(const float4*)pb;
  float4 Cv = *(const float4*)pc;
  float4 D  = *(const float4*)pd;
  ushort4 u;
  u.x = f2bf(wa * A.x + wb * Bv.x + wc * Cv.x + wd * D.x);
  u.y = f2bf(wa * A.y + wb * Bv.y + wc * Cv.y + wd * D.y);
  u.z = f2bf(wa * A.z + wb * Bv.z + wc * Cv.z + wd * D.z);
  u.w = f2bf(wa * A.w + wb * Bv.w + wc * Cv.w + wd * D.w);
  unsigned short* out = sp + ((size_t)(bl * HP + h + 1) * WP + (w + 1)) * CS_ + t * 64 + c;
  *(ushort4*)out = u;
}

// ---------------- implicit-im2col MFMA GEMM: out[p,f] = sum_k A[p,k]*W[k,f] + b[f]
// M-tile = 128 px (one image row), N = 128 (all F), BK = 64.
__global__ __launch_bounds__(256, 2) void gemm_kernel(
    const unsigned short* __restrict__ sp,   // (nb,130,130,576) bf16
    const unsigned short* __restrict__ Wt,   // (128,5184) bf16
    const float* __restrict__ bias,
    float* __restrict__ out, int b0) {
  __shared__ __align__(16) short lds[16384]; // A:[0,8192) B:[8192,16384) shorts
  const int tid  = threadIdx.x;
  const int lane = tid & 63;
  const int wv   = tid >> 6;
  const int bl   = blockIdx.x / H_;
  const int h    = blockIdx.x % H_;
  const int wm   = (wv >> 1) * 64;
  const int wn   = (wv & 1) * 64;
  const int l15  = lane & 15;
  const int quad = lane >> 4;
  const int sub  = lane & 7;
  const int rig  = lane >> 3;   // row-in-group for staging

  f32x4 acc[4][4] = {};

  // LDS fragment read offsets (in shorts), XOR-swizzled
  int a_addr[2][4], b_addr[2][4];
#pragma unroll
  for (int ks = 0; ks < 2; ++ks) {
#pragma unroll
    for (int i = 0; i < 4; ++i) {
      int m = wm + 16 * i + l15;
      int q = ks * 4 + quad;
      a_addr[ks][i] = m * 64 + (q ^ (m & 7)) * 8;
      int n = wn + 16 * i + l15;
      b_addr[ks][i] = 8192 + n * 64 + (q ^ (n & 7)) * 8;
    }
  }

  // staging row/swizzle per instruction (4 A + 4 B per wave)
  int am[4], asg[4];
  const short* gB[4];
#pragma unroll
  for (int i = 0; i < 4; ++i) {
    int m  = wv * 32 + i * 8 + rig;
    am[i]  = m;
    asg[i] = (sub ^ (m & 7)) * 8;
    gB[i]  = (const short*)Wt + (size_t)m * KDIM + (sub ^ (m & 7)) * 8;
  }

  for (int tap = 0; tap < 9; ++tap) {
    const int ky = tap / 3, kx = tap % 3;
    const short* gA[4];
#pragma unroll
    for (int i = 0; i < 4; ++i)
      gA[i] = (const short*)sp +
              ((size_t)((bl * HP + h + ky) * WP) + (am[i] + kx)) * CS_ + asg[i];
    for (int tcs = 0; tcs < 9; ++tcs) {
      __syncthreads();   // all waves done reading previous tile
#pragma unroll
      for (int i = 0; i < 4; ++i) {
        __builtin_amdgcn_global_load_lds(
            (const __attribute__((address_space(1))) void*)(gA[i]),
            (__attribute__((address_space(3))) void*)&lds[(wv * 32 + i * 8) * 64],
            16, 0, 0);
        gA[i] += 64;
      }
#pragma unroll
      for (int i = 0; i < 4; ++i) {
        __builtin_amdgcn_global_load_lds(
            (const __attribute__((address_space(1))) void*)(gB[i]),
            (__attribute__((address_space(3))) void*)&lds[8192 + (wv * 32 + i * 8) * 64],
            16, 0, 0);
        gB[i] += 64;
      }
      __syncthreads();   // staged data visible
#pragma unroll
      for (int ks = 0; ks < 2; ++ks) {
        bf16x8 af[4], bf[4];
#pragma unroll
        for (int i = 0; i < 4; ++i) af[i] = *(const bf16x8*)&lds[a_addr[ks][i]];
#pragma unroll
        for (int j = 0; j < 4; ++j) bf[j] = *(const bf16x8*)&lds[b_addr[ks][j]];
#pragma unroll
        for (int i = 0; i < 4; ++i)
#pragma unroll
          for (int j = 0; j < 4; ++j)
            acc[i][j] = __builtin_amdgcn_mfma_f32_16x16x32_bf16(
                af[i], bf[j], acc[i][j], 0, 0, 0);
      }
    }
  }

  // epilogue: C row = quad*4+r, col = lane&15 (within each 16x16 frag)
  const int b = b0 + bl;
  float bj[4];
#pragma unroll
  for (int j = 0; j < 4; ++j) bj[j] = bias[wn + 16 * j + l15];
  float* op = out + (size_t)(b * H_ + h) * W_ * F_;
#pragma unroll
  for (int i = 0; i < 4; ++i) {
#pragma unroll
    for (int r = 0; r < 4; ++r) {
      int m = wm + 16 * i + quad * 4 + r;
      float* rp = op + (size_t)m * F_;
#pragma unroll
      for (int j = 0; j < 4; ++j)
        rp[wn + 16 * j + l15] = acc[i][j][r] + bj[j];
    }
  }
}

extern "C" void kernel_launch(void* const* d_in, const int* in_sizes, int n_in,
                              void* d_out, int out_size, void* d_ws, size_t ws_size,
                              hipStream_t stream) {
  (void)in_sizes; (void)n_in; (void)out_size;
  const float* x    = (const float*)d_in[0];
  const float* Woff = (const float*)d_in[1];
  const float* boff = (const float*)d_in[2];
  const float* Wf   = (const float*)d_in[3];
  const float* bias = (const float*)d_in[4];
  float* out = (float*)d_out;

  char* ws = (char*)d_ws;
  size_t off_bytes = (size_t)B_ * H_ * W_ * 18 * 4;  // 9.44 MB
  size_t wt_bytes  = (size_t)F_ * KDIM * 2;          // 1.33 MB
  size_t p1 = (off_bytes + 255) & ~(size_t)255;
  size_t p2 = (p1 + wt_bytes + 255) & ~(size_t)255;
  float*          offs = (float*)ws;
  unsigned short* Wt   = (unsigned short*)(ws + p1);
  unsigned short* sp   = (unsigned short*)(ws + p2);

  size_t per_batch = (size_t)HP * WP * CS_ * 2;      // 19.47 MB
  size_t avail = (ws_size > p2) ? (ws_size - p2) : 0;
  int nb = (int)(avail / per_batch);
  if (nb < 1) nb = 1;
  if (nb > B_) nb = B_;

  offs_conv_kernel<<<(B_ * H_ * W_) / 64, 256, 0, stream>>>(x, Woff, boff, offs);
  wt_prep_kernel<<<(KDIM * F_ + 255) / 256, 256, 0, stream>>>(Wf, Wt);

  for (int b0 = 0; b0 < B_; b0 += nb) {
    int cur = (B_ - b0 < nb) ? (B_ - b0) : nb;
    int bzN = cur * 516 * 9;
    border_zero_kernel<<<(bzN + 255) / 256, 256, 0, stream>>>(sp, cur);
    int smN = cur * H_ * W_ * KK_;
    sample_kernel<<<(smN * 16 + 255) / 256, 256, 0, stream>>>(x, offs, sp, b0, cur);
    gemm_kernel<<<cur * H_, 256, 0, stream>>>(sp, Wt, bias, out, b0);
  }
}

// Round 3
// 490.409 us; speedup vs baseline: 1.6804x; 1.0397x over previous
//
#include <hip/hip_runtime.h>
#include <hip/hip_bf16.h>

#define B_   8
#define H_   128
#define W_   128
#define C_   64
#define F_   128
#define KK_  9
#define CS_  576      // KK_*C_
#define KDIM 5184     // 9*CS_
#define HP   130
#define WP   130

typedef __bf16 bf16x8 __attribute__((ext_vector_type(8)));
typedef float  f32x4  __attribute__((ext_vector_type(4)));

__device__ __forceinline__ unsigned short f2bf(float f) {
  unsigned int u = __float_as_uint(f);
  unsigned int r = (u + 0x7fffu + ((u >> 16) & 1u)) >> 16;
  return (unsigned short)r;
}

// ---------------- offset conv: offs[b,h,w,18] = SAME conv3x3(x, W_off) + b_off
// 4 lanes per pixel (16 ch each): coalesced x reads, shuffle-reduce the 18 sums.
__global__ __launch_bounds__(256) void offs_conv_kernel(
    const float* __restrict__ x, const float* __restrict__ Woff,
    const float* __restrict__ boff, float* __restrict__ offs) {
  __shared__ float Wl[9 * 18 * 64];   // [tap][o][c]
  const int tid = threadIdx.x;
  for (int i = tid; i < 9 * 64 * 18; i += 256) {
    int tap = i / 1152;
    int r   = i % 1152;
    int c   = r / 18;
    int o   = r % 18;
    Wl[(tap * 18 + o) * 64 + c] = Woff[i];
  }
  __syncthreads();
  const int gpix = blockIdx.x * 64 + (tid >> 2);
  const int q    = tid & 3;
  const int c0   = q * 16;
  const int w = gpix % W_;
  const int h = (gpix / W_) % H_;
  const int b = gpix / (W_ * H_);
  float acc[18] = {};
  for (int ky = 0; ky < 3; ++ky) {
    int hy = h + ky - 1;
    if (hy < 0 || hy >= H_) continue;
    for (int kx = 0; kx < 3; ++kx) {
      int wx = w + kx - 1;
      if (wx < 0 || wx >= W_) continue;
      const float* xp = x + ((size_t)(b * H_ + hy) * W_ + wx) * C_ + c0;
      const float* wl = &Wl[(ky * 3 + kx) * 18 * 64 + c0];
      float4 xv0 = *(const float4*)(xp + 0);
      float4 xv1 = *(const float4*)(xp + 4);
      float4 xv2 = *(const float4*)(xp + 8);
      float4 xv3 = *(const float4*)(xp + 12);
#pragma unroll
      for (int o = 0; o < 18; ++o) {
        const float4* wv = (const float4*)(wl + o * 64);
        float4 w0 = wv[0], w1 = wv[1], w2 = wv[2], w3 = wv[3];
        acc[o] += xv0.x * w0.x + xv0.y * w0.y + xv0.z * w0.z + xv0.w * w0.w
                + xv1.x * w1.x + xv1.y * w1.y + xv1.z * w1.z + xv1.w * w1.w
                + xv2.x * w2.x + xv2.y * w2.y + xv2.z * w2.z + xv2.w * w2.w
                + xv3.x * w3.x + xv3.y * w3.y + xv3.z * w3.z + xv3.w * w3.w;
      }
    }
  }
#pragma unroll
  for (int o = 0; o < 18; ++o) {
    acc[o] += __shfl_xor(acc[o], 1);
    acc[o] += __shfl_xor(acc[o], 2);
  }
  float* op = offs + (size_t)gpix * 18;
  for (int o = q; o < 18; o += 4) op[o] = acc[o] + boff[o];
}

// ---------------- W (5184,128) fp32 -> Wt (128,5184) bf16, LDS-tiled transpose
__global__ __launch_bounds__(256) void wt_prep_kernel(
    const float* __restrict__ Wf, unsigned short* __restrict__ Wt) {
  __shared__ float Wl[64][65];
  const int tid = threadIdx.x;
  const int kk0 = (blockIdx.x % 81) * 64;
  const int f0  = (blockIdx.x / 81) * 64;
  for (int i = tid; i < 4096; i += 256) {
    int kk = i >> 6, f = i & 63;
    Wl[kk][f] = Wf[(size_t)(kk0 + kk) * F_ + f0 + f];
  }
  __syncthreads();
  for (int i = tid; i < 4096; i += 256) {
    int f = i >> 6, kk = i & 63;
    Wt[(size_t)(f0 + f) * KDIM + kk0 + kk] = f2bf(Wl[kk][f]);
  }
}

// ---------------- zero the 1-pixel border of padded sampled
__global__ __launch_bounds__(256) void border_zero_kernel(
    unsigned short* __restrict__ sp, int nb) {
  int tid = blockIdx.x * 256 + threadIdx.x;
  int total = nb * 516 * 9;
  if (tid >= total) return;
  int cc  = (tid % 9) * 64;
  int pix = tid / 9;
  int bl  = pix / 516;
  int p   = pix % 516;
  int hp, wp;
  if (p < 130)      { hp = 0;   wp = p; }
  else if (p < 260) { hp = 129; wp = p - 130; }
  else { int q = p - 260; hp = 1 + (q >> 1); wp = (q & 1) ? 129 : 0; }
  unsigned short* dst = sp + ((size_t)(bl * HP + hp) * WP + wp) * CS_ + cc;
  uint4 z = {0u, 0u, 0u, 0u};
#pragma unroll
  for (int i = 0; i < 8; ++i) ((uint4*)dst)[i] = z;
}

// ---------------- bilinear sampling -> padded bf16 sampled (nb,130,130,576)
// 8 lanes per (pixel,tap), 8 channels/lane: 16B stores, 8 gathers in flight.
__global__ __launch_bounds__(256) void sample_kernel(
    const float* __restrict__ x, const float* __restrict__ offs,
    unsigned short* __restrict__ sp, int b0, int nb) {
  int gid = blockIdx.x * 32 + (threadIdx.x >> 3);
  int l   = threadIdx.x & 7;
  int total = nb * H_ * W_ * KK_;
  if (gid >= total) return;
  int t  = gid % 9;
  int w  = (gid / 9) % W_;
  int h  = (gid / (9 * W_)) % H_;
  int bl = gid / (9 * W_ * H_);
  int b  = b0 + bl;
  const float* op = offs + (((size_t)(b * H_ + h) * W_ + w) * 18 + 2 * t);
  float offx = op[0], offy = op[1];
  float lx = (float)w + (float)(t % 3 - 1) + offx;
  float ly = (float)h + (float)(t / 3 - 1) + offy;
  lx = fminf(fmaxf(lx, 0.f), 127.f);
  ly = fminf(fmaxf(ly, 0.f), 127.f);
  float fx = floorf(lx), fy = floorf(ly);
  float x0 = fminf(fmaxf(fx, 0.f), 127.f);
  float x1 = fminf(fmaxf(fx + 1.f, 0.f), 127.f);
  float y0 = fminf(fmaxf(fy, 0.f), 127.f);
  float y1 = fminf(fmaxf(fy + 1.f, 0.f), 127.f);
  float wa = (x1 - lx) * (y1 - ly);
  float wb = (x1 - lx) * (ly - y0);
  float wc = (lx - x0) * (y1 - ly);
  float wd = (lx - x0) * (ly - y0);
  int ix0 = (int)x0, ix1 = (int)x1, iy0 = (int)y0, iy1 = (int)y1;
  const float* xb = x + (size_t)b * (H_ * W_ * C_);
  const int c = l * 8;
  const float* pa = xb + ((size_t)iy0 * W_ + ix0) * C_ + c;
  const float* pb = xb + ((size_t)iy1 * W_ + ix0) * C_ + c;
  const float* pc = xb + ((size_t)iy0 * W_ + ix1) * C_ + c;
  const float* pd = xb + ((size_t)iy1 * W_ + ix1) * C_ + c;
  float4 A0 = ((const float4*)pa)[0], A1 = ((const float4*)pa)[1];
  float4 B0 = ((const float4*)pb)[0], B1 = ((const float4*)pb)[1];
  float4 C0 = ((const float4*)pc)[0], C1 = ((const float4*)pc)[1];
  float4 D0 = ((const float4*)pd)[0], D1 = ((const float4*)pd)[1];
  union { ushort s[8]; uint4 v; } u;
  u.s[0] = f2bf(wa * A0.x + wb * B0.x + wc * C0.x + wd * D0.x);
  u.s[1] = f2bf(wa * A0.y + wb * B0.y + wc * C0.y + wd * D0.y);
  u.s[2] = f2bf(wa * A0.z + wb * B0.z + wc * C0.z + wd * D0.z);
  u.s[3] = f2bf(wa * A0.w + wb * B0.w + wc * C0.w + wd * D0.w);
  u.s[4] = f2bf(wa * A1.x + wb * B1.x + wc * C1.x + wd * D1.x);
  u.s[5] = f2bf(wa * A1.y + wb * B1.y + wc * C1.y + wd * D1.y);
  u.s[6] = f2bf(wa * A1.z + wb * B1.z + wc * C1.z + wd * D1.z);
  u.s[7] = f2bf(wa * A1.w + wb * B1.w + wc * C1.w + wd * D1.w);
  unsigned short* out = sp + ((size_t)(bl * HP + h + 1) * WP + (w + 1)) * CS_ + t * 64 + c;
  *(uint4*)out = u.v;
}

// ---------------- implicit-im2col MFMA GEMM: out[p,f] = sum_k A[p,k]*W[k,f] + b[f]
// M-tile = 128 px (one image row), N = 128 (all F), BK = 64.
// blockIdx is XCD-banded: each XCD owns a contiguous band of rows for L2 reuse.
__global__ __launch_bounds__(256, 4) void gemm_kernel(
    const unsigned short* __restrict__ sp,   // (nb,130,130,576) bf16
    const unsigned short* __restrict__ Wt,   // (128,5184) bf16
    const float* __restrict__ bias,
    float* __restrict__ out, int b0) {
  __shared__ __align__(16) short lds[16384]; // A:[0,8192) B:[8192,16384) shorts
  const int tid  = threadIdx.x;
  const int lane = tid & 63;
  const int wv   = tid >> 6;
  // XCD-banded row swizzle (gridDim.x is always a multiple of 8 here)
  const int g8   = gridDim.x >> 3;
  const int gr   = (blockIdx.x & 7) * g8 + (blockIdx.x >> 3);
  const int bl   = gr / H_;
  const int h    = gr % H_;
  const int wm   = (wv >> 1) * 64;
  const int wn   = (wv & 1) * 64;
  const int l15  = lane & 15;
  const int quad = lane >> 4;
  const int sub  = lane & 7;
  const int rig  = lane >> 3;   // row-in-group for staging

  f32x4 acc[4][4] = {};

  // LDS fragment read offsets (in shorts), XOR-swizzled
  int a_addr[2][4], b_addr[2][4];
#pragma unroll
  for (int ks = 0; ks < 2; ++ks) {
#pragma unroll
    for (int i = 0; i < 4; ++i) {
      int m = wm + 16 * i + l15;
      int q = ks * 4 + quad;
      a_addr[ks][i] = m * 64 + (q ^ (m & 7)) * 8;
      int n = wn + 16 * i + l15;
      b_addr[ks][i] = 8192 + n * 64 + (q ^ (n & 7)) * 8;
    }
  }

  // staging row/swizzle per instruction (4 A + 4 B per wave)
  int am[4], asg[4];
  const short* gB[4];
#pragma unroll
  for (int i = 0; i < 4; ++i) {
    int m  = wv * 32 + i * 8 + rig;
    am[i]  = m;
    asg[i] = (sub ^ (m & 7)) * 8;
    gB[i]  = (const short*)Wt + (size_t)m * KDIM + (sub ^ (m & 7)) * 8;
  }

  for (int tap = 0; tap < 9; ++tap) {
    const int ky = tap / 3, kx = tap % 3;
    const short* gA[4];
#pragma unroll
    for (int i = 0; i < 4; ++i)
      gA[i] = (const short*)sp +
              ((size_t)((bl * HP + h + ky) * WP) + (am[i] + kx)) * CS_ + asg[i];
    for (int tcs = 0; tcs < 9; ++tcs) {
      __syncthreads();   // all waves done reading previous tile
#pragma unroll
      for (int i = 0; i < 4; ++i) {
        __builtin_amdgcn_global_load_lds(
            (const __attribute__((address_space(1))) void*)(gA[i]),
            (__attribute__((address_space(3))) void*)&lds[(wv * 32 + i * 8) * 64],
            16, 0, 0);
        gA[i] += 64;
      }
#pragma unroll
      for (int i = 0; i < 4; ++i) {
        __builtin_amdgcn_global_load_lds(
            (const __attribute__((address_space(1))) void*)(gB[i]),
            (__attribute__((address_space(3))) void*)&lds[8192 + (wv * 32 + i * 8) * 64],
            16, 0, 0);
        gB[i] += 64;
      }
      __syncthreads();   // staged data visible
#pragma unroll
      for (int ks = 0; ks < 2; ++ks) {
        bf16x8 af[4], bf[4];
#pragma unroll
        for (int i = 0; i < 4; ++i) af[i] = *(const bf16x8*)&lds[a_addr[ks][i]];
#pragma unroll
        for (int j = 0; j < 4; ++j) bf[j] = *(const bf16x8*)&lds[b_addr[ks][j]];
#pragma unroll
        for (int i = 0; i < 4; ++i)
#pragma unroll
          for (int j = 0; j < 4; ++j)
            acc[i][j] = __builtin_amdgcn_mfma_f32_16x16x32_bf16(
                af[i], bf[j], acc[i][j], 0, 0, 0);
      }
    }
  }

  // epilogue: C row = quad*4+r, col = lane&15 (within each 16x16 frag)
  const int b = b0 + bl;
  float bj[4];
#pragma unroll
  for (int j = 0; j < 4; ++j) bj[j] = bias[wn + 16 * j + l15];
  float* op = out + (size_t)(b * H_ + h) * W_ * F_;
#pragma unroll
  for (int i = 0; i < 4; ++i) {
#pragma unroll
    for (int r = 0; r < 4; ++r) {
      int m = wm + 16 * i + quad * 4 + r;
      float* rp = op + (size_t)m * F_;
#pragma unroll
      for (int j = 0; j < 4; ++j)
        rp[wn + 16 * j + l15] = acc[i][j][r] + bj[j];
    }
  }
}

extern "C" void kernel_launch(void* const* d_in, const int* in_sizes, int n_in,
                              void* d_out, int out_size, void* d_ws, size_t ws_size,
                              hipStream_t stream) {
  (void)in_sizes; (void)n_in; (void)out_size;
  const float* x    = (const float*)d_in[0];
  const float* Woff = (const float*)d_in[1];
  const float* boff = (const float*)d_in[2];
  const float* Wf   = (const float*)d_in[3];
  const float* bias = (const float*)d_in[4];
  float* out = (float*)d_out;

  char* ws = (char*)d_ws;
  size_t off_bytes = (size_t)B_ * H_ * W_ * 18 * 4;  // 9.44 MB
  size_t wt_bytes  = (size_t)F_ * KDIM * 2;          // 1.33 MB
  size_t p1 = (off_bytes + 255) & ~(size_t)255;
  size_t p2 = (p1 + wt_bytes + 255) & ~(size_t)255;
  float*          offs = (float*)ws;
  unsigned short* Wt   = (unsigned short*)(ws + p1);
  unsigned short* sp   = (unsigned short*)(ws + p2);

  size_t per_batch = (size_t)HP * WP * CS_ * 2;      // 19.47 MB
  size_t avail = (ws_size > p2) ? (ws_size - p2) : 0;
  int nb = (int)(avail / per_batch);
  if (nb < 1) nb = 1;
  if (nb > B_) nb = B_;

  offs_conv_kernel<<<(B_ * H_ * W_) / 64, 256, 0, stream>>>(x, Woff, boff, offs);
  wt_prep_kernel<<<162, 256, 0, stream>>>(Wf, Wt);

  for (int b0 = 0; b0 < B_; b0 += nb) {
    int cur = (B_ - b0 < nb) ? (B_ - b0) : nb;
    int bzN = cur * 516 * 9;
    border_zero_kernel<<<(bzN + 255) / 256, 256, 0, stream>>>(sp, cur);
    int smN = cur * H_ * W_ * KK_;
    sample_kernel<<<(smN + 31) / 32, 256, 0, stream>>>(x, offs, sp, b0, cur);
    gemm_kernel<<<cur * H_, 256, 0, stream>>>(sp, Wt, bias, out, b0);
  }
}

// Round 4
// 410.445 us; speedup vs baseline: 2.0078x; 1.1948x over previous
//
#include <hip/hip_runtime.h>
#include <hip/hip_bf16.h>

#define B_   8
#define H_   128
#define W_   128
#define C_   64
#define F_   128
#define KDIM 5184     // 9 taps * 576
#define BHW_ 131072   // B_*H_*W_

// fused-tile geometry
#define TH   8
#define TW   16
#define HY   10       // TH+2
#define HX   18       // TW+2
#define NPX  180      // HY*HX

// LDS layout (units: shorts)
#define STILE 0       // 180*64            = 11520 shorts (sampled tap-t tile, swizzled)
#define BTILE 11520   // 3 chunks *128*64  = 24576 shorts (W slices, swizzled)
#define PARMW 36096   // 180 float4        =  1440 shorts (bilinear weights)
#define PARMO 37536   // 180 int4          =  1440 shorts (corner offsets + px)
#define LDSSZ 38976   // 77952 B -> 2 blocks/CU

typedef __bf16 bf16x8 __attribute__((ext_vector_type(8)));
typedef float  f32x4  __attribute__((ext_vector_type(4)));

__device__ __forceinline__ unsigned short f2bf(float f) {
  unsigned int u = __float_as_uint(f);
  unsigned int r = (u + 0x7fffu + ((u >> 16) & 1u)) >> 16;
  return (unsigned short)r;
}

// ---------------- offset conv -> PLANAR offsets: offsP[o][b,h,w]
__global__ __launch_bounds__(256) void offs_conv_kernel(
    const float* __restrict__ x, const float* __restrict__ Woff,
    const float* __restrict__ boff, float* __restrict__ offsP) {
  __shared__ float Wl[9 * 18 * 64];   // [tap][o][c]
  const int tid = threadIdx.x;
  for (int i = tid; i < 9 * 64 * 18; i += 256) {
    int tap = i / 1152;
    int r   = i % 1152;
    int c   = r / 18;
    int o   = r % 18;
    Wl[(tap * 18 + o) * 64 + c] = Woff[i];
  }
  __syncthreads();
  const int gpix = blockIdx.x * 64 + (tid >> 2);
  const int q    = tid & 3;
  const int c0   = q * 16;
  const int w = gpix % W_;
  const int h = (gpix / W_) % H_;
  const int b = gpix / (W_ * H_);
  float acc[18] = {};
  for (int ky = 0; ky < 3; ++ky) {
    int hy = h + ky - 1;
    if (hy < 0 || hy >= H_) continue;
    for (int kx = 0; kx < 3; ++kx) {
      int wx = w + kx - 1;
      if (wx < 0 || wx >= W_) continue;
      const float* xp = x + ((size_t)(b * H_ + hy) * W_ + wx) * C_ + c0;
      const float* wl = &Wl[(ky * 3 + kx) * 18 * 64 + c0];
      float4 xv0 = *(const float4*)(xp + 0);
      float4 xv1 = *(const float4*)(xp + 4);
      float4 xv2 = *(const float4*)(xp + 8);
      float4 xv3 = *(const float4*)(xp + 12);
#pragma unroll
      for (int o = 0; o < 18; ++o) {
        const float4* wvp = (const float4*)(wl + o * 64);
        float4 w0 = wvp[0], w1 = wvp[1], w2 = wvp[2], w3 = wvp[3];
        acc[o] += xv0.x * w0.x + xv0.y * w0.y + xv0.z * w0.z + xv0.w * w0.w
                + xv1.x * w1.x + xv1.y * w1.y + xv1.z * w1.z + xv1.w * w1.w
                + xv2.x * w2.x + xv2.y * w2.y + xv2.z * w2.z + xv2.w * w2.w
                + xv3.x * w3.x + xv3.y * w3.y + xv3.z * w3.z + xv3.w * w3.w;
      }
    }
  }
#pragma unroll
  for (int o = 0; o < 18; ++o) {
    acc[o] += __shfl_xor(acc[o], 1);
    acc[o] += __shfl_xor(acc[o], 2);
  }
  for (int o = q; o < 18; o += 4)
    offsP[(size_t)o * BHW_ + gpix] = acc[o] + boff[o];
}

// ---------------- W (5184,128) fp32 -> Wt (128,5184) bf16, LDS-tiled transpose
__global__ __launch_bounds__(256) void wt_prep_kernel(
    const float* __restrict__ Wf, unsigned short* __restrict__ Wt) {
  __shared__ float Wl[64][65];
  const int tid = threadIdx.x;
  const int kk0 = (blockIdx.x % 81) * 64;
  const int f0  = (blockIdx.x / 81) * 64;
  for (int i = tid; i < 4096; i += 256) {
    int kk = i >> 6, f = i & 63;
    Wl[kk][f] = Wf[(size_t)(kk0 + kk) * F_ + f0 + f];
  }
  __syncthreads();
  for (int i = tid; i < 4096; i += 256) {
    int f = i >> 6, kk = i & 63;
    Wt[(size_t)(f0 + f) * KDIM + kk0 + kk] = f2bf(Wl[kk][f]);
  }
}

// ---------------- fused bilinear-sample + implicit-im2col MFMA conv
// grid = 1024 blocks (XCD-banded: one image per XCD), block = 256 (4 waves).
__global__ __launch_bounds__(256, 2) void fused_kernel(
    const float* __restrict__ x, const float* __restrict__ offsP,
    const unsigned short* __restrict__ Wt, const float* __restrict__ bias,
    float* __restrict__ out) {
  __shared__ __align__(16) short lds[LDSSZ];
  const int tid  = threadIdx.x;
  const int lane = tid & 63;
  const int wv   = tid >> 6;
  // XCD-banded decode: blocks (bid&7) own image (bid&7)
  const int gr   = (blockIdx.x & 7) * 128 + (blockIdx.x >> 3);
  const int b    = gr >> 7;
  const int tile = gr & 127;
  const int ty   = tile >> 3, tx = tile & 7;
  const int gy0  = ty * TH, gx0 = tx * TW;
  const float* xb = x + (size_t)b * (H_ * W_ * C_);

  const int l15  = lane & 15, quad = lane >> 4;
  const int sub  = lane & 7,  rig  = lane >> 3;
  const int wm   = (wv >> 1) * 64, wn = (wv & 1) * 64;

  f32x4 acc[4][4] = {};

  // A-frag pixel-index base per m-frag i: my = (wv>>1)*4 + i, p0 = my*HX + l15
  int p0[4];
#pragma unroll
  for (int i = 0; i < 4; ++i) p0[i] = ((wv >> 1) * 4 + i) * HX + l15;
  // B-frag LDS offsets (chunk 0): row n = wn+16j+l15, swizzle (ks*4+quad)^(l15&7)
  int bo[2][4];
#pragma unroll
  for (int ks = 0; ks < 2; ++ks)
#pragma unroll
    for (int j = 0; j < 4; ++j)
      bo[ks][j] = BTILE + (wn + 16 * j + l15) * 64 + (((ks * 4 + quad) ^ (l15 & 7)) * 8);

  const int s_py = tid / HX, s_px = tid - s_py * HX;   // S1 task coords (tid<180)

  for (int t = 0; t < 9; ++t) {
    __syncthreads();   // all waves done reading stile/params of t-1
    // ---- S1: per-halo-pixel bilinear params
    if (tid < NPX) {
      int gy = gy0 + s_py - 1, gx = gx0 + s_px - 1;
      float wa = 0.f, wb = 0.f, wc = 0.f, wd = 0.f;
      int oA = 0, oB = 0, oC = 0, oD = 0;
      if ((unsigned)gy < (unsigned)H_ && (unsigned)gx < (unsigned)W_) {
        int pix = (b * H_ + gy) * W_ + gx;
        float offx = offsP[(size_t)(2 * t) * BHW_ + pix];
        float offy = offsP[(size_t)(2 * t + 1) * BHW_ + pix];
        float lx = (float)gx + (float)(t % 3 - 1) + offx;
        float ly = (float)gy + (float)(t / 3 - 1) + offy;
        lx = fminf(fmaxf(lx, 0.f), 127.f);
        ly = fminf(fmaxf(ly, 0.f), 127.f);
        float fx = floorf(lx), fy = floorf(ly);
        float x0c = fminf(fmaxf(fx, 0.f), 127.f);
        float x1c = fminf(fmaxf(fx + 1.f, 0.f), 127.f);
        float y0c = fminf(fmaxf(fy, 0.f), 127.f);
        float y1c = fminf(fmaxf(fy + 1.f, 0.f), 127.f);
        wa = (x1c - lx) * (y1c - ly);
        wb = (x1c - lx) * (ly - y0c);
        wc = (lx - x0c) * (y1c - ly);
        wd = (lx - x0c) * (ly - y0c);
        int ix0 = (int)x0c, ix1 = (int)x1c, iy0 = (int)y0c, iy1 = (int)y1c;
        oA = (iy0 * W_ + ix0) * C_;
        oB = (iy1 * W_ + ix0) * C_;
        oC = (iy0 * W_ + ix1) * C_;
        oD = (iy1 * W_ + ix1) * C_;
      }
      ((float4*)&lds[PARMW])[tid] = make_float4(wa, wb, wc, wd);
      ((int4*)&lds[PARMO])[tid]  = make_int4(oA | (s_px << 20), oB, oC, oD);
    }
    __syncthreads();   // params visible
    // ---- S2: gather + blend + bf16 pack into stile (1440 tasks)
#pragma unroll
    for (int it = 0; it < 6; ++it) {
      int u = it * 256 + tid;
      if (u < NPX * 8) {
        int p = u >> 3, j = u & 7;
        float4 wv4 = ((const float4*)&lds[PARMW])[p];
        int4   ov4 = ((const int4*)&lds[PARMO])[p];
        int pxl = ov4.x >> 20;
        const float* pa = xb + (ov4.x & 0xFFFFF) + j * 8;
        const float* pb = xb + ov4.y + j * 8;
        const float* pc = xb + ov4.z + j * 8;
        const float* pd = xb + ov4.w + j * 8;
        float4 A0 = ((const float4*)pa)[0], A1 = ((const float4*)pa)[1];
        float4 B0 = ((const float4*)pb)[0], B1 = ((const float4*)pb)[1];
        float4 C0 = ((const float4*)pc)[0], C1 = ((const float4*)pc)[1];
        float4 D0 = ((const float4*)pd)[0], D1 = ((const float4*)pd)[1];
        union { unsigned short s[8]; uint4 v; } uu;
        uu.s[0] = f2bf(wv4.x * A0.x + wv4.y * B0.x + wv4.z * C0.x + wv4.w * D0.x);
        uu.s[1] = f2bf(wv4.x * A0.y + wv4.y * B0.y + wv4.z * C0.y + wv4.w * D0.y);
        uu.s[2] = f2bf(wv4.x * A0.z + wv4.y * B0.z + wv4.z * C0.z + wv4.w * D0.z);
        uu.s[3] = f2bf(wv4.x * A0.w + wv4.y * B0.w + wv4.z * C0.w + wv4.w * D0.w);
        uu.s[4] = f2bf(wv4.x * A1.x + wv4.y * B1.x + wv4.z * C1.x + wv4.w * D1.x);
        uu.s[5] = f2bf(wv4.x * A1.y + wv4.y * B1.y + wv4.z * C1.y + wv4.w * D1.y);
        uu.s[6] = f2bf(wv4.x * A1.z + wv4.y * B1.z + wv4.z * C1.z + wv4.w * D1.z);
        uu.s[7] = f2bf(wv4.x * A1.w + wv4.y * B1.w + wv4.z * C1.w + wv4.w * D1.w);
        *(uint4*)&lds[STILE + p * 64 + ((j ^ (pxl & 7)) * 8)] = uu.v;
      }
    }
    // ---- conv: 3 ky2 groups; per group stage 3 kx2 W-chunks (48 KB) then MFMA
    for (int g = 0; g < 3; ++g) {
      __syncthreads();   // btile free (and on g=0: stile writes ordered before reads)
#pragma unroll
      for (int i = 0; i < 12; ++i) {
        int slot = wv * 12 + i;              // 0..47
        int chunk = slot >> 4;               // kx2
        int f = ((slot & 15) * 8) + rig;
        int tap2 = g * 3 + chunk;
        const short* src = (const short*)Wt + (size_t)f * KDIM +
                           tap2 * 576 + t * 64 + ((sub ^ rig) * 8);
        __builtin_amdgcn_global_load_lds(
            (const __attribute__((address_space(1))) void*)src,
            (__attribute__((address_space(3))) void*)&lds[BTILE + slot * 512],
            16, 0, 0);
      }
      __syncthreads();   // staged visible + stile visible
      const int off2 = g * HX;               // ky2 = g
#pragma unroll
      for (int c3 = 0; c3 < 3; ++c3) {       // kx2 = c3
        int t1 = (l15 + c3) & 7;
        int xr0 = ((quad ^ t1) * 8);
        int xr1 = (((4 + quad) ^ t1) * 8);
#pragma unroll
        for (int ks = 0; ks < 2; ++ks) {
          int xr = ks ? xr1 : xr0;
          bf16x8 af[4], bfr[4];
#pragma unroll
          for (int i = 0; i < 4; ++i)
            af[i] = *(const bf16x8*)&lds[(p0[i] + off2 + c3) * 64 + xr];
#pragma unroll
          for (int j = 0; j < 4; ++j)
            bfr[j] = *(const bf16x8*)&lds[bo[ks][j] + c3 * 8192];
#pragma unroll
          for (int i = 0; i < 4; ++i)
#pragma unroll
            for (int j = 0; j < 4; ++j)
              acc[i][j] = __builtin_amdgcn_mfma_f32_16x16x32_bf16(
                  af[i], bfr[j], acc[i][j], 0, 0, 0);
        }
      }
    }
  }

  // ---- epilogue
  float bj[4];
#pragma unroll
  for (int j = 0; j < 4; ++j) bj[j] = bias[wn + 16 * j + l15];
#pragma unroll
  for (int i = 0; i < 4; ++i) {
    int gy = gy0 + (wv >> 1) * 4 + i;
#pragma unroll
    for (int r = 0; r < 4; ++r) {
      int gx = gx0 + quad * 4 + r;
      float* rp = out + ((size_t)((b * H_ + gy) * W_ + gx)) * F_;
#pragma unroll
      for (int j = 0; j < 4; ++j)
        rp[wn + 16 * j + l15] = acc[i][j][r] + bj[j];
    }
  }
}

extern "C" void kernel_launch(void* const* d_in, const int* in_sizes, int n_in,
                              void* d_out, int out_size, void* d_ws, size_t ws_size,
                              hipStream_t stream) {
  (void)in_sizes; (void)n_in; (void)out_size; (void)ws_size;
  const float* x    = (const float*)d_in[0];
  const float* Woff = (const float*)d_in[1];
  const float* boff = (const float*)d_in[2];
  const float* Wf   = (const float*)d_in[3];
  const float* bias = (const float*)d_in[4];
  float* out = (float*)d_out;

  char* ws = (char*)d_ws;
  size_t off_bytes = (size_t)18 * BHW_ * 4;          // 9.44 MB planar offsets
  size_t p1 = (off_bytes + 255) & ~(size_t)255;
  float*          offsP = (float*)ws;
  unsigned short* Wt    = (unsigned short*)(ws + p1); // 1.33 MB

  offs_conv_kernel<<<BHW_ / 64, 256, 0, stream>>>(x, Woff, boff, offsP);
  wt_prep_kernel<<<162, 256, 0, stream>>>(Wf, Wt);
  fused_kernel<<<1024, 256, 0, stream>>>(x, offsP, Wt, bias, out);
}